// Round 1
// baseline (14167.725 us; speedup 1.0000x reference)
//
#include <hip/hip_runtime.h>
#include <math.h>

// Problem constants
static constexpr int H  = 512;
static constexpr int B  = 32;
static constexpr int S  = 128;
static constexpr int G4 = 2048;  // 4*H

// ws layout (in floats)
static constexpr size_t OFF_E  = 0;                       // [t][c][b] : S*G4*B
static constexpr size_t SZ_E   = (size_t)S * G4 * B;      // 8,388,608
static constexpr size_t OFF_D  = OFF_E + SZ_E;            // [b][t][c] : B*S*G4
static constexpr size_t SZ_D   = (size_t)B * S * G4;
static constexpr size_t OFF_EO = OFF_D + SZ_D;            // enc_out [b][t][h]
static constexpr size_t SZ_EO  = (size_t)B * S * H;
static constexpr size_t OFF_PT = OFF_EO + SZ_EO;          // P_t [b][h][s]
static constexpr size_t SZ_PT  = (size_t)B * H * S;
static constexpr size_t OFF_H  = OFF_PT + SZ_PT;          // h_buf [b][h]
static constexpr size_t OFF_C  = OFF_H + (size_t)B * H;   // c_buf [b][h]
static constexpr size_t OFF_DP = OFF_C + (size_t)B * H;   // dp [b][h]
static constexpr size_t OFF_M1 = OFF_DP + (size_t)B * H;  // M1 [c][2]
static constexpr size_t OFF_BE = OFF_M1 + (size_t)G4 * 2; // bias_e [c]
static constexpr size_t OFF_DB = OFF_BE + G4;             // dbias [c]
static constexpr size_t OFF_END= OFF_DB + G4;             // floats end
// ints after OFF_END: top_idx[32], then 2 unsigned barrier counters

__device__ __forceinline__ float sigm(float x){
  float e = __expf(-x);
  return 1.0f / (1.0f + e);
}
__device__ __forceinline__ float tanh_(float x){
  float e = __expf(2.0f * x);
  return 1.0f - 2.0f / (1.0f + e);
}

// -------- grid barrier: monotone counter, agent-scope --------
__device__ __forceinline__ void gbar(unsigned* cnt, unsigned target){
  __syncthreads();
  if (threadIdx.x == 0){
    __threadfence();  // release: wb
    __hip_atomic_fetch_add(cnt, 1u, __ATOMIC_RELAXED, __HIP_MEMORY_SCOPE_AGENT);
    while (__hip_atomic_load(cnt, __ATOMIC_RELAXED, __HIP_MEMORY_SCOPE_AGENT) < target){
      __builtin_amdgcn_s_sleep(1);
    }
    __threadfence();  // acquire: inv
  }
  __syncthreads();
}

// -------- prep: M1 = Wih@Wp, bias_e = Wih@bp + bih + bhh, dbias --------
__global__ __launch_bounds__(256) void prep_misc(
    const float* __restrict__ eWih, const float* __restrict__ Wp,
    const float* __restrict__ bp,  const float* __restrict__ ebih,
    const float* __restrict__ ebhh, const float* __restrict__ dbih,
    const float* __restrict__ dbhh,
    float* __restrict__ M1, float* __restrict__ bias_e, float* __restrict__ dbias)
{
  int c = blockIdx.x * 256 + threadIdx.x;   // 0..2047
  const float* wr = eWih + (size_t)c * H;
  float m0 = 0.f, m1 = 0.f, mb = 0.f;
  for (int k = 0; k < H; k += 4){
    float4 w  = *(const float4*)(wr + k);
    float4 p0 = *(const float4*)(Wp + (size_t)k * 2);
    float4 p1 = *(const float4*)(Wp + (size_t)(k + 2) * 2);
    float4 bb = *(const float4*)(bp + k);
    m0 += w.x*p0.x + w.y*p0.z + w.z*p1.x + w.w*p1.z;
    m1 += w.x*p0.y + w.y*p0.w + w.z*p1.y + w.w*p1.w;
    mb += w.x*bb.x + w.y*bb.y + w.z*bb.z + w.w*bb.w;
  }
  M1[(size_t)c*2]   = m0;
  M1[(size_t)c*2+1] = m1;
  bias_e[c] = ebih[c] + ebhh[c] + mb;
  dbias[c]  = dbih[c] + dbhh[c];
}

// -------- E fill: E[t][c][b] = M1[c]·in[b,t] + bias_e[c] --------
__global__ __launch_bounds__(256) void efill(
    const float* __restrict__ inp, const float* __restrict__ M1,
    const float* __restrict__ be, float* __restrict__ E)
{
  size_t i = (size_t)blockIdx.x * 256 + threadIdx.x;  // S*G4*B total
  int b = (int)(i & 31);
  int c = (int)((i >> 5) & 2047);
  int t = (int)(i >> 16);
  float x0 = inp[((size_t)b * S + t) * 2 + 0];
  float x1 = inp[((size_t)b * S + t) * 2 + 1];
  E[i] = M1[(size_t)c*2] * x0 + M1[(size_t)c*2+1] * x1 + be[c];
}

// -------- generic fp32 GEMM: C = A(MxK) @ B(NxK)^T (+bias) --------
// LAYOUT 0: C[m*N+n]   LAYOUT 1: P_t[b][n][t] with m = b*128+t
template<int LAYOUT>
__global__ __launch_bounds__(256) void gemm_nt(
    const float* __restrict__ A, const float* __restrict__ Bm,
    const float* __restrict__ bias, float* __restrict__ C,
    int M, int N, int K)
{
  __shared__ float As[16][68];
  __shared__ float Bs[16][68];
  int tid = threadIdx.x;
  int bm = blockIdx.y * 64, bn = blockIdx.x * 64;
  int tm = (tid & 15) * 4, tn = (tid >> 4) * 4;
  float acc[4][4] = {};
  int r  = tid >> 2;
  int kq = (tid & 3) * 4;
  for (int k0 = 0; k0 < K; k0 += 16){
    float4 a = *(const float4*)(A  + (size_t)(bm + r) * K + k0 + kq);
    float4 b = *(const float4*)(Bm + (size_t)(bn + r) * K + k0 + kq);
    __syncthreads();
    As[kq+0][r] = a.x; As[kq+1][r] = a.y; As[kq+2][r] = a.z; As[kq+3][r] = a.w;
    Bs[kq+0][r] = b.x; Bs[kq+1][r] = b.y; Bs[kq+2][r] = b.z; Bs[kq+3][r] = b.w;
    __syncthreads();
    #pragma unroll
    for (int kk = 0; kk < 16; ++kk){
      float4 av = *(const float4*)(&As[kk][tm]);
      float4 bv = *(const float4*)(&Bs[kk][tn]);
      acc[0][0] += av.x*bv.x; acc[0][1] += av.x*bv.y; acc[0][2] += av.x*bv.z; acc[0][3] += av.x*bv.w;
      acc[1][0] += av.y*bv.x; acc[1][1] += av.y*bv.y; acc[1][2] += av.y*bv.z; acc[1][3] += av.y*bv.w;
      acc[2][0] += av.z*bv.x; acc[2][1] += av.z*bv.y; acc[2][2] += av.z*bv.z; acc[2][3] += av.z*bv.w;
      acc[3][0] += av.w*bv.x; acc[3][1] += av.w*bv.y; acc[3][2] += av.w*bv.z; acc[3][3] += av.w*bv.w;
    }
  }
  #pragma unroll
  for (int i = 0; i < 4; ++i){
    int m = bm + tm + i;
    #pragma unroll
    for (int j = 0; j < 4; ++j){
      int n = bn + tn + j;
      float vv = acc[i][j] + (bias ? bias[n] : 0.f);
      if (LAYOUT == 0) C[(size_t)m * N + n] = vv;
      else             C[((size_t)(m >> 7) * 512 + n) * 128 + (m & 127)] = vv;
    }
  }
}

// -------- persistent encoder --------
__global__ __launch_bounds__(256) void encoder_kernel(
    const float* __restrict__ Whh,   // enc_Whh (2048x512)
    const float* __restrict__ E,     // [t][c][b]
    float* __restrict__ h_buf, float* __restrict__ c_buf,
    float* __restrict__ enc_out, unsigned* __restrict__ bcnt)
{
  __shared__ float hsh[B * H];       // swizzled
  __shared__ float gsh[2][4][B];
  const int tid = threadIdx.x, bk = blockIdx.x;
  const int b = tid & 31, gate = (tid >> 5) & 3, jj = tid >> 7;
  const int row = gate * H + bk * 2 + jj;
  const float* wrow = Whh + (size_t)row * H;
  const int bx = b & 7;
  float creg = 0.f;
  unsigned bar = 0;
  for (int t = 0; t < S; ++t){
    for (int i = tid; i < B * (H/4); i += 256){
      int bb = i >> 7, k4 = i & 127;
      *(float4*)&hsh[bb * H + ((k4 ^ (bb & 7)) << 2)] =
        *(const float4*)(h_buf + (size_t)bb * H + (k4 << 2));
    }
    __syncthreads();
    float ev = E[((size_t)t * G4 + row) * B + b];
    float a0=0.f,a1=0.f,a2=0.f,a3=0.f;
    const float* hb = hsh + b * H;
    #pragma unroll 2
    for (int k4 = 0; k4 < 128; k4 += 4){
      float4 w0 = *(const float4*)(wrow + ((k4+0) << 2));
      float4 q0 = *(const float4*)(hb + (((k4+0) ^ bx) << 2));
      a0 = fmaf(w0.w,q0.w, fmaf(w0.z,q0.z, fmaf(w0.y,q0.y, fmaf(w0.x,q0.x, a0))));
      float4 w1 = *(const float4*)(wrow + ((k4+1) << 2));
      float4 q1 = *(const float4*)(hb + (((k4+1) ^ bx) << 2));
      a1 = fmaf(w1.w,q1.w, fmaf(w1.z,q1.z, fmaf(w1.y,q1.y, fmaf(w1.x,q1.x, a1))));
      float4 w2 = *(const float4*)(wrow + ((k4+2) << 2));
      float4 q2 = *(const float4*)(hb + (((k4+2) ^ bx) << 2));
      a2 = fmaf(w2.w,q2.w, fmaf(w2.z,q2.z, fmaf(w2.y,q2.y, fmaf(w2.x,q2.x, a2))));
      float4 w3 = *(const float4*)(wrow + ((k4+3) << 2));
      float4 q3 = *(const float4*)(hb + (((k4+3) ^ bx) << 2));
      a3 = fmaf(w3.w,q3.w, fmaf(w3.z,q3.z, fmaf(w3.y,q3.y, fmaf(w3.x,q3.x, a3))));
    }
    gsh[jj][gate][b] = ev + ((a0 + a1) + (a2 + a3));
    __syncthreads();
    if (tid < 64){
      int b2 = tid & 31, jj2 = tid >> 5;
      float iv = sigm (gsh[jj2][0][b2]);
      float fv = sigm (gsh[jj2][1][b2]);
      float gv = tanh_(gsh[jj2][2][b2]);
      float ov = sigm (gsh[jj2][3][b2]);
      creg = fv * creg + iv * gv;
      float hnew = ov * tanh_(creg);
      int j2 = bk * 2 + jj2;
      h_buf[(size_t)b2 * H + j2] = hnew;
      enc_out[((size_t)b2 * S + t) * H + j2] = hnew;
    }
    gbar(bcnt, 256u * (++bar));
  }
  if (tid < 64){
    int b2 = tid & 31, jj2 = tid >> 5;
    c_buf[(size_t)b2 * H + bk * 2 + jj2] = creg;
  }
}

// -------- persistent decoder --------
__global__ __launch_bounds__(256) void decoder_kernel(
    const float* __restrict__ Whh,    // dec_Whh
    const float* __restrict__ D,      // [b][t][c]
    const float* __restrict__ dbias,  // 2048
    const float* __restrict__ W2,     // (512x512)
    const float* __restrict__ Pt,     // [b][h][s]
    const float* __restrict__ v,      // 512
    float* __restrict__ h_buf, float* __restrict__ c_buf,
    float* __restrict__ dp, int* __restrict__ top_idx,
    float* __restrict__ out, unsigned* __restrict__ bcnt)
{
  __shared__ float hsh[B * H];
  __shared__ float gsh[2][4][B];
  __shared__ float gshB[2][4][B];
  __shared__ float dpsh[H];
  __shared__ float vsh[H];
  __shared__ float scsh[2][S];
  __shared__ float rv[S];
  __shared__ int   ri[S];
  const int tid = threadIdx.x, bk = blockIdx.x;
  const int b = tid & 31, gate = (tid >> 5) & 3, jj = tid >> 7;
  const int row = gate * H + bk * 2 + jj;
  const float* wrow = Whh + (size_t)row * H;
  const int bx = b & 7;
  float creg = 0.f;
  if (tid < 64) creg = c_buf[(size_t)(tid & 31) * H + bk * 2 + (tid >> 5)];
  if (bk < 32){ vsh[tid] = v[tid]; vsh[tid + 256] = v[tid + 256]; }
  unsigned bar = 0;
  for (int t = 0; t < S; ++t){
    // ---------------- phase A: gates + pointwise ----------------
    for (int i = tid; i < B * (H/4); i += 256){
      int bb = i >> 7, k4 = i & 127;
      *(float4*)&hsh[bb * H + ((k4 ^ (bb & 7)) << 2)] =
        *(const float4*)(h_buf + (size_t)bb * H + (k4 << 2));
    }
    __syncthreads();
    float xterm;
    if (t == 0) xterm = dbias[row];
    else        xterm = D[((size_t)b * S + top_idx[b]) * G4 + row];
    float a0=0.f,a1=0.f,a2=0.f,a3=0.f;
    const float* hb = hsh + b * H;
    #pragma unroll 2
    for (int k4 = 0; k4 < 128; k4 += 4){
      float4 w0 = *(const float4*)(wrow + ((k4+0) << 2));
      float4 q0 = *(const float4*)(hb + (((k4+0) ^ bx) << 2));
      a0 = fmaf(w0.w,q0.w, fmaf(w0.z,q0.z, fmaf(w0.y,q0.y, fmaf(w0.x,q0.x, a0))));
      float4 w1 = *(const float4*)(wrow + ((k4+1) << 2));
      float4 q1 = *(const float4*)(hb + (((k4+1) ^ bx) << 2));
      a1 = fmaf(w1.w,q1.w, fmaf(w1.z,q1.z, fmaf(w1.y,q1.y, fmaf(w1.x,q1.x, a1))));
      float4 w2 = *(const float4*)(wrow + ((k4+2) << 2));
      float4 q2 = *(const float4*)(hb + (((k4+2) ^ bx) << 2));
      a2 = fmaf(w2.w,q2.w, fmaf(w2.z,q2.z, fmaf(w2.y,q2.y, fmaf(w2.x,q2.x, a2))));
      float4 w3 = *(const float4*)(wrow + ((k4+3) << 2));
      float4 q3 = *(const float4*)(hb + (((k4+3) ^ bx) << 2));
      a3 = fmaf(w3.w,q3.w, fmaf(w3.z,q3.z, fmaf(w3.y,q3.y, fmaf(w3.x,q3.x, a3))));
    }
    gsh[jj][gate][b] = xterm + ((a0 + a1) + (a2 + a3));
    __syncthreads();
    if (tid < 64){
      int b2 = tid & 31, jj2 = tid >> 5;
      float iv = sigm (gsh[jj2][0][b2]);
      float fv = sigm (gsh[jj2][1][b2]);
      float gv = tanh_(gsh[jj2][2][b2]);
      float ov = sigm (gsh[jj2][3][b2]);
      creg = fv * creg + iv * gv;
      float hnew = ov * tanh_(creg);
      h_buf[(size_t)b2 * H + bk * 2 + jj2] = hnew;
    }
    gbar(bcnt, 256u * (++bar));
    // ---------------- phase B: dp = h @ W2^T (blocks 0..127, 4 cols each) ----
    if (bk < 128){
      for (int i = tid; i < B * (H/4); i += 256){
        int bb = i >> 7, k4 = i & 127;
        *(float4*)&hsh[bb * H + ((k4 ^ (bb & 7)) << 2)] =
          *(const float4*)(h_buf + (size_t)bb * H + (k4 << 2));
      }
      __syncthreads();
      int kq = tid >> 7, nn = (tid >> 5) & 3, b2 = tid & 31;
      int n = bk * 4 + nn;
      const float* w = W2 + (size_t)n * H + kq * 256;
      const float* hb2 = hsh + b2 * H;
      int bx2 = b2 & 7;
      float p0 = 0.f, p1 = 0.f;
      #pragma unroll 2
      for (int k4 = 0; k4 < 64; k4 += 2){
        float4 w0 = *(const float4*)(w + ((k4+0) << 2));
        int kk0 = kq * 64 + k4 + 0;
        float4 h0 = *(const float4*)(hb2 + ((kk0 ^ bx2) << 2));
        p0 = fmaf(w0.w,h0.w, fmaf(w0.z,h0.z, fmaf(w0.y,h0.y, fmaf(w0.x,h0.x, p0))));
        float4 w1 = *(const float4*)(w + ((k4+1) << 2));
        int kk1 = kq * 64 + k4 + 1;
        float4 h1 = *(const float4*)(hb2 + ((kk1 ^ bx2) << 2));
        p1 = fmaf(w1.w,h1.w, fmaf(w1.z,h1.z, fmaf(w1.y,h1.y, fmaf(w1.x,h1.x, p1))));
      }
      gshB[kq][nn][b2] = p0 + p1;
      __syncthreads();
      if (tid < 128){
        int nn2 = tid >> 5, b3 = tid & 31;
        dp[(size_t)b3 * H + bk * 4 + nn2] = gshB[0][nn2][b3] + gshB[1][nn2][b3];
      }
    }
    gbar(bcnt, 256u * (++bar));
    // ---------------- phase C: attention + softmax + argmax (blocks 0..31) ---
    if (bk < 32){
      dpsh[tid]       = dp[(size_t)bk * H + tid];
      dpsh[tid + 256] = dp[(size_t)bk * H + 256 + tid];
      __syncthreads();
      int s = tid & 127, half = tid >> 7;
      const float* Pp = Pt + ((size_t)bk * H + half * 256) * S + s;
      float c0=0.f,c1=0.f,c2=0.f,c3=0.f;
      #pragma unroll 2
      for (int h = 0; h < 256; h += 4){
        float x0 = Pp[(size_t)(h+0) * S] + dpsh[half*256 + h + 0];
        c0 += vsh[half*256 + h + 0] * tanh_(x0);
        float x1 = Pp[(size_t)(h+1) * S] + dpsh[half*256 + h + 1];
        c1 += vsh[half*256 + h + 1] * tanh_(x1);
        float x2 = Pp[(size_t)(h+2) * S] + dpsh[half*256 + h + 2];
        c2 += vsh[half*256 + h + 2] * tanh_(x2);
        float x3 = Pp[(size_t)(h+3) * S] + dpsh[half*256 + h + 3];
        c3 += vsh[half*256 + h + 3] * tanh_(x3);
      }
      scsh[half][s] = (c0 + c1) + (c2 + c3);
      __syncthreads();
      float sc = 0.f;
      if (tid < 128){
        sc = scsh[0][tid] + scsh[1][tid];
        rv[tid] = sc; ri[tid] = tid;
      }
      __syncthreads();
      for (int off = 64; off > 0; off >>= 1){
        if (tid < off){
          float v2 = rv[tid + off]; int i2 = ri[tid + off];
          if (v2 > rv[tid] || (v2 == rv[tid] && i2 < ri[tid])){ rv[tid] = v2; ri[tid] = i2; }
        }
        __syncthreads();
      }
      float m = rv[0]; int am = ri[0];
      __syncthreads();
      if (tid < 128) rv[tid] = __expf(sc - m);
      __syncthreads();
      for (int off = 64; off > 0; off >>= 1){
        if (tid < off) rv[tid] += rv[tid + off];
        __syncthreads();
      }
      float lse = __logf(rv[0]);
      if (tid < 128) out[((size_t)bk * S + t) * S + tid] = sc - m - lse;
      if (tid == 0) top_idx[bk] = am;
    }
    gbar(bcnt, 256u * (++bar));
  }
}

extern "C" void kernel_launch(void* const* d_in, const int* in_sizes, int n_in,
                              void* d_out, int out_size, void* d_ws, size_t ws_size,
                              hipStream_t stream) {
  const float* inputs  = (const float*)d_in[0];
  const float* Wp      = (const float*)d_in[1];
  const float* bp      = (const float*)d_in[2];
  const float* eWih    = (const float*)d_in[3];
  const float* eWhh    = (const float*)d_in[4];
  const float* ebih    = (const float*)d_in[5];
  const float* ebhh    = (const float*)d_in[6];
  const float* dWih    = (const float*)d_in[7];
  const float* dWhh    = (const float*)d_in[8];
  const float* dbih    = (const float*)d_in[9];
  const float* dbhh    = (const float*)d_in[10];
  const float* W1      = (const float*)d_in[11];
  const float* W2      = (const float*)d_in[12];
  const float* v       = (const float*)d_in[13];
  float* out = (float*)d_out;

  float* ws = (float*)d_ws;
  float* E      = ws + OFF_E;
  float* D      = ws + OFF_D;
  float* enc_out= ws + OFF_EO;
  float* Pt     = ws + OFF_PT;
  float* h_buf  = ws + OFF_H;
  float* c_buf  = ws + OFF_C;
  float* dp     = ws + OFF_DP;
  float* M1     = ws + OFF_M1;
  float* bias_e = ws + OFF_BE;
  float* dbias  = ws + OFF_DB;
  int*      top_idx = (int*)(ws + OFF_END);
  unsigned* bcnt    = (unsigned*)(top_idx + 32);  // [0]=encoder, [1]=decoder

  // zero h0 and barrier counters (deterministic across graph replays)
  hipMemsetAsync(h_buf, 0, (size_t)B * H * sizeof(float), stream);
  hipMemsetAsync(bcnt, 0, 2 * sizeof(unsigned), stream);

  prep_misc<<<G4 / 256, 256, 0, stream>>>(eWih, Wp, bp, ebih, ebhh, dbih, dbhh,
                                          M1, bias_e, dbias);
  efill<<<(int)(SZ_E / 256), 256, 0, stream>>>(inputs, M1, bias_e, E);

  encoder_kernel<<<256, 256, 0, stream>>>(eWhh, E, h_buf, c_buf, enc_out, &bcnt[0]);

  // D = enc_out @ dWih^T + dbias   (M=4096, N=2048, K=512)
  {
    dim3 grid(G4 / 64, (B * S) / 64);
    gemm_nt<0><<<grid, 256, 0, stream>>>(enc_out, dWih, dbias, D, B * S, G4, H);
  }
  // Pt = (enc_out @ W1^T) transposed to [b][h][s]  (M=4096, N=512, K=512)
  {
    dim3 grid(H / 64, (B * S) / 64);
    gemm_nt<1><<<grid, 256, 0, stream>>>(enc_out, W1, nullptr, Pt, B * S, H, H);
  }

  decoder_kernel<<<256, 256, 0, stream>>>(dWhh, D, dbias, W2, Pt, v,
                                          h_buf, c_buf, dp, top_idx, out, &bcnt[1]);
  (void)in_sizes; (void)n_in; (void)out_size; (void)ws_size;
}

// Round 2
// 6269.481 us; speedup vs baseline: 2.2598x; 2.2598x over previous
//
#include <hip/hip_runtime.h>
#include <math.h>

// Problem constants
static constexpr int H  = 512;
static constexpr int B  = 32;
static constexpr int S  = 128;
static constexpr int G4 = 2048;  // 4*H
static constexpr int BH = B * H;

// ws layout (in floats)
static constexpr size_t OFF_E  = 0;                       // [t][c][b] : S*G4*B
static constexpr size_t SZ_E   = (size_t)S * G4 * B;
static constexpr size_t OFF_D  = OFF_E + SZ_E;            // [b][t][c] : B*S*G4
static constexpr size_t SZ_D   = (size_t)B * S * G4;
static constexpr size_t OFF_EO = OFF_D + SZ_D;            // enc_out [b][t][h]
static constexpr size_t SZ_EO  = (size_t)B * S * H;
static constexpr size_t OFF_PT = OFF_EO + SZ_EO;          // P_t [b][h][s]
static constexpr size_t SZ_PT  = (size_t)B * H * S;
static constexpr size_t OFF_H  = OFF_PT + SZ_PT;          // h ping-pong [2][b][h]
static constexpr size_t OFF_C  = OFF_H + 2 * (size_t)BH;  // c_buf [b][h]
static constexpr size_t OFF_DP = OFF_C + (size_t)BH;      // dp [b][h]
static constexpr size_t OFF_M1 = OFF_DP + (size_t)BH;     // M1 [c][2]
static constexpr size_t OFF_BE = OFF_M1 + (size_t)G4 * 2; // bias_e [c]
static constexpr size_t OFF_DB = OFF_BE + G4;             // dbias [c]
static constexpr size_t OFF_END= OFF_DB + G4;             // floats end
// int region at OFF_END: top_idx[32], then 2 barrier areas of 1088 u32 each
static constexpr int BAR_U32 = 1088;  // sub[32*32] + root line[32] + go line[32]

__device__ __forceinline__ float sigm(float x){
  float e = __expf(-x);
  return 1.0f / (1.0f + e);
}
__device__ __forceinline__ float tanh_(float x){
  float e = __expf(2.0f * x);
  return 1.0f - 2.0f / (1.0f + e);
}

// coherent-point (device-scope) accessors: bypass stale L1/L2, no fences needed
__device__ __forceinline__ float cload(const float* p){
  return __hip_atomic_load(p, __ATOMIC_RELAXED, __HIP_MEMORY_SCOPE_AGENT);
}
__device__ __forceinline__ void cstore(float* p, float v){
  __hip_atomic_store(p, v, __ATOMIC_RELAXED, __HIP_MEMORY_SCOPE_AGENT);
}
__device__ __forceinline__ int cloadi(const int* p){
  return __hip_atomic_load(p, __ATOMIC_RELAXED, __HIP_MEMORY_SCOPE_AGENT);
}
__device__ __forceinline__ void cstorei(int* p, int v){
  __hip_atomic_store(p, v, __ATOMIC_RELAXED, __HIP_MEMORY_SCOPE_AGENT);
}

// -------- hierarchical fence-free grid barrier (grid = 256 blocks) --------
// bar_area: [g*32] sub-counter for group g (32 groups of 8 blocks),
//           [1024] root, [1056] go.  ep is 1-based barrier index.
// Correctness: __syncthreads() drains every wave's vmcnt (compiler inserts
// s_waitcnt vmcnt(0) before s_barrier), so all this block's device-scope
// stores are at the coherence point before the relaxed arrive-add.
__device__ __forceinline__ void gbar(unsigned* bar_area, unsigned ep){
  __syncthreads();
  if (threadIdx.x == 0){
    unsigned* sub  = bar_area + ((blockIdx.x >> 3) << 5);
    unsigned* root = bar_area + 1024;
    unsigned* go   = bar_area + 1056;
    unsigned o = __hip_atomic_fetch_add(sub, 1u, __ATOMIC_RELAXED, __HIP_MEMORY_SCOPE_AGENT);
    if (o == ep * 8u - 1u){
      unsigned r = __hip_atomic_fetch_add(root, 1u, __ATOMIC_RELAXED, __HIP_MEMORY_SCOPE_AGENT);
      if (r == ep * 32u - 1u)
        __hip_atomic_store(go, ep, __ATOMIC_RELAXED, __HIP_MEMORY_SCOPE_AGENT);
    }
    while (__hip_atomic_load(go, __ATOMIC_RELAXED, __HIP_MEMORY_SCOPE_AGENT) < ep){}
  }
  __syncthreads();
}

// -------- prep: M1 = Wih@Wp, bias_e = Wih@bp + bih + bhh, dbias --------
__global__ __launch_bounds__(256) void prep_misc(
    const float* __restrict__ eWih, const float* __restrict__ Wp,
    const float* __restrict__ bp,  const float* __restrict__ ebih,
    const float* __restrict__ ebhh, const float* __restrict__ dbih,
    const float* __restrict__ dbhh,
    float* __restrict__ M1, float* __restrict__ bias_e, float* __restrict__ dbias)
{
  int c = blockIdx.x * 256 + threadIdx.x;   // 0..2047
  const float* wr = eWih + (size_t)c * H;
  float m0 = 0.f, m1 = 0.f, mb = 0.f;
  for (int k = 0; k < H; k += 4){
    float4 w  = *(const float4*)(wr + k);
    float4 p0 = *(const float4*)(Wp + (size_t)k * 2);
    float4 p1 = *(const float4*)(Wp + (size_t)(k + 2) * 2);
    float4 bb = *(const float4*)(bp + k);
    m0 += w.x*p0.x + w.y*p0.z + w.z*p1.x + w.w*p1.z;
    m1 += w.x*p0.y + w.y*p0.w + w.z*p1.y + w.w*p1.w;
    mb += w.x*bb.x + w.y*bb.y + w.z*bb.z + w.w*bb.w;
  }
  M1[(size_t)c*2]   = m0;
  M1[(size_t)c*2+1] = m1;
  bias_e[c] = ebih[c] + ebhh[c] + mb;
  dbias[c]  = dbih[c] + dbhh[c];
}

// -------- E fill: E[t][c][b] = M1[c]·in[b,t] + bias_e[c] --------
__global__ __launch_bounds__(256) void efill(
    const float* __restrict__ inp, const float* __restrict__ M1,
    const float* __restrict__ be, float* __restrict__ E)
{
  size_t i = (size_t)blockIdx.x * 256 + threadIdx.x;
  int b = (int)(i & 31);
  int c = (int)((i >> 5) & 2047);
  int t = (int)(i >> 16);
  float x0 = inp[((size_t)b * S + t) * 2 + 0];
  float x1 = inp[((size_t)b * S + t) * 2 + 1];
  E[i] = M1[(size_t)c*2] * x0 + M1[(size_t)c*2+1] * x1 + be[c];
}

// -------- generic fp32 GEMM: C = A(MxK) @ B(NxK)^T (+bias) --------
template<int LAYOUT>
__global__ __launch_bounds__(256) void gemm_nt(
    const float* __restrict__ A, const float* __restrict__ Bm,
    const float* __restrict__ bias, float* __restrict__ C,
    int M, int N, int K)
{
  __shared__ float As[16][68];
  __shared__ float Bs[16][68];
  int tid = threadIdx.x;
  int bm = blockIdx.y * 64, bn = blockIdx.x * 64;
  int tm = (tid & 15) * 4, tn = (tid >> 4) * 4;
  float acc[4][4] = {};
  int r  = tid >> 2;
  int kq = (tid & 3) * 4;
  for (int k0 = 0; k0 < K; k0 += 16){
    float4 a = *(const float4*)(A  + (size_t)(bm + r) * K + k0 + kq);
    float4 b = *(const float4*)(Bm + (size_t)(bn + r) * K + k0 + kq);
    __syncthreads();
    As[kq+0][r] = a.x; As[kq+1][r] = a.y; As[kq+2][r] = a.z; As[kq+3][r] = a.w;
    Bs[kq+0][r] = b.x; Bs[kq+1][r] = b.y; Bs[kq+2][r] = b.z; Bs[kq+3][r] = b.w;
    __syncthreads();
    #pragma unroll
    for (int kk = 0; kk < 16; ++kk){
      float4 av = *(const float4*)(&As[kk][tm]);
      float4 bv = *(const float4*)(&Bs[kk][tn]);
      acc[0][0] += av.x*bv.x; acc[0][1] += av.x*bv.y; acc[0][2] += av.x*bv.z; acc[0][3] += av.x*bv.w;
      acc[1][0] += av.y*bv.x; acc[1][1] += av.y*bv.y; acc[1][2] += av.y*bv.z; acc[1][3] += av.y*bv.w;
      acc[2][0] += av.z*bv.x; acc[2][1] += av.z*bv.y; acc[2][2] += av.z*bv.z; acc[2][3] += av.z*bv.w;
      acc[3][0] += av.w*bv.x; acc[3][1] += av.w*bv.y; acc[3][2] += av.w*bv.z; acc[3][3] += av.w*bv.w;
    }
  }
  #pragma unroll
  for (int i = 0; i < 4; ++i){
    int m = bm + tm + i;
    #pragma unroll
    for (int j = 0; j < 4; ++j){
      int n = bn + tn + j;
      float vv = acc[i][j] + (bias ? bias[n] : 0.f);
      if (LAYOUT == 0) C[(size_t)m * N + n] = vv;
      else             C[((size_t)(m >> 7) * 512 + n) * 128 + (m & 127)] = vv;
    }
  }
}

// -------- persistent encoder --------
__global__ __launch_bounds__(256) void encoder_kernel(
    const float* __restrict__ Whh,
    const float* __restrict__ E,     // [t][c][b]
    float* __restrict__ h_pp,        // [2][B][H] ping-pong
    float* __restrict__ c_buf,
    float* __restrict__ enc_out, unsigned* __restrict__ bars)
{
  __shared__ float hsh[BH];
  __shared__ float gsh[2][4][B];
  const int tid = threadIdx.x, bk = blockIdx.x;
  const int b = tid & 31, gate = (tid >> 5) & 3, jj = tid >> 7;
  const int row = gate * H + bk * 2 + jj;
  const float* wrow = Whh + (size_t)row * H;
  const int bx = b & 7;
  float creg = 0.f;
  unsigned bar = 0;
  for (int t = 0; t < S; ++t){
    const float* hsrc = h_pp + (size_t)(t & 1) * BH;
    float*       hdst = h_pp + (size_t)((t & 1) ^ 1) * BH;
    for (int i = tid; i < BH / 4; i += 256){
      int bb = i >> 7, k4 = i & 127;
      const float* src = hsrc + (size_t)bb * H + (k4 << 2);
      float4 vv;
      vv.x = cload(src+0); vv.y = cload(src+1); vv.z = cload(src+2); vv.w = cload(src+3);
      *(float4*)&hsh[bb * H + ((k4 ^ (bb & 7)) << 2)] = vv;
    }
    __syncthreads();
    float ev = E[((size_t)t * G4 + row) * B + b];
    float a0=0.f,a1=0.f,a2=0.f,a3=0.f;
    const float* hb = hsh + b * H;
    #pragma unroll 2
    for (int k4 = 0; k4 < 128; k4 += 4){
      float4 w0 = *(const float4*)(wrow + ((k4+0) << 2));
      float4 q0 = *(const float4*)(hb + (((k4+0) ^ bx) << 2));
      a0 = fmaf(w0.w,q0.w, fmaf(w0.z,q0.z, fmaf(w0.y,q0.y, fmaf(w0.x,q0.x, a0))));
      float4 w1 = *(const float4*)(wrow + ((k4+1) << 2));
      float4 q1 = *(const float4*)(hb + (((k4+1) ^ bx) << 2));
      a1 = fmaf(w1.w,q1.w, fmaf(w1.z,q1.z, fmaf(w1.y,q1.y, fmaf(w1.x,q1.x, a1))));
      float4 w2 = *(const float4*)(wrow + ((k4+2) << 2));
      float4 q2 = *(const float4*)(hb + (((k4+2) ^ bx) << 2));
      a2 = fmaf(w2.w,q2.w, fmaf(w2.z,q2.z, fmaf(w2.y,q2.y, fmaf(w2.x,q2.x, a2))));
      float4 w3 = *(const float4*)(wrow + ((k4+3) << 2));
      float4 q3 = *(const float4*)(hb + (((k4+3) ^ bx) << 2));
      a3 = fmaf(w3.w,q3.w, fmaf(w3.z,q3.z, fmaf(w3.y,q3.y, fmaf(w3.x,q3.x, a3))));
    }
    gsh[jj][gate][b] = ev + ((a0 + a1) + (a2 + a3));
    __syncthreads();
    if (tid < 64){
      int b2 = tid & 31, jj2 = tid >> 5;
      float iv = sigm (gsh[jj2][0][b2]);
      float fv = sigm (gsh[jj2][1][b2]);
      float gv = tanh_(gsh[jj2][2][b2]);
      float ov = sigm (gsh[jj2][3][b2]);
      creg = fv * creg + iv * gv;
      float hnew = ov * tanh_(creg);
      int j2 = bk * 2 + jj2;
      cstore(hdst + (size_t)b2 * H + j2, hnew);
      enc_out[((size_t)b2 * S + t) * H + j2] = hnew;
    }
    gbar(bars, ++bar);
  }
  if (tid < 64){
    int b2 = tid & 31, jj2 = tid >> 5;
    c_buf[(size_t)b2 * H + bk * 2 + jj2] = creg;
  }
}

// -------- persistent decoder --------
__global__ __launch_bounds__(256) void decoder_kernel(
    const float* __restrict__ Whh,
    const float* __restrict__ D,      // [b][t][c]
    const float* __restrict__ dbias,
    const float* __restrict__ W2,
    const float* __restrict__ Pt,     // [b][h][s]
    const float* __restrict__ v,
    float* __restrict__ h_pp,         // [2][B][H]; enc final h in buf0
    float* __restrict__ c_buf,
    float* __restrict__ dp, int* __restrict__ top_idx,
    float* __restrict__ out, unsigned* __restrict__ bars)
{
  __shared__ float hsh[BH];
  __shared__ float gsh[2][4][B];
  __shared__ float gshB[2][4][B];
  __shared__ float dpsh[H];
  __shared__ float vsh[H];
  __shared__ float scsh[2][S];
  __shared__ float rv[S];
  __shared__ int   ri[S];
  const int tid = threadIdx.x, bk = blockIdx.x;
  const int b = tid & 31, gate = (tid >> 5) & 3, jj = tid >> 7;
  const int row = gate * H + bk * 2 + jj;
  const float* wrow = Whh + (size_t)row * H;
  const int bx = b & 7;
  float creg = 0.f;
  if (tid < 64) creg = c_buf[(size_t)(tid & 31) * H + bk * 2 + (tid >> 5)];
  if (bk < 32){ vsh[tid] = v[tid]; vsh[tid + 256] = v[tid + 256]; }
  unsigned bar = 0;
  for (int t = 0; t < S; ++t){
    const float* hsrc = h_pp + (size_t)(t & 1) * BH;
    float*       hdst = h_pp + (size_t)((t & 1) ^ 1) * BH;
    // ---------------- phase A: gates + pointwise ----------------
    for (int i = tid; i < BH / 4; i += 256){
      int bb = i >> 7, k4 = i & 127;
      const float* src = hsrc + (size_t)bb * H + (k4 << 2);
      float4 vv;
      vv.x = cload(src+0); vv.y = cload(src+1); vv.z = cload(src+2); vv.w = cload(src+3);
      *(float4*)&hsh[bb * H + ((k4 ^ (bb & 7)) << 2)] = vv;
    }
    __syncthreads();
    float xterm;
    if (t == 0) xterm = dbias[row];
    else        xterm = D[((size_t)b * S + cloadi(top_idx + b)) * G4 + row];
    float a0=0.f,a1=0.f,a2=0.f,a3=0.f;
    const float* hb = hsh + b * H;
    #pragma unroll 2
    for (int k4 = 0; k4 < 128; k4 += 4){
      float4 w0 = *(const float4*)(wrow + ((k4+0) << 2));
      float4 q0 = *(const float4*)(hb + (((k4+0) ^ bx) << 2));
      a0 = fmaf(w0.w,q0.w, fmaf(w0.z,q0.z, fmaf(w0.y,q0.y, fmaf(w0.x,q0.x, a0))));
      float4 w1 = *(const float4*)(wrow + ((k4+1) << 2));
      float4 q1 = *(const float4*)(hb + (((k4+1) ^ bx) << 2));
      a1 = fmaf(w1.w,q1.w, fmaf(w1.z,q1.z, fmaf(w1.y,q1.y, fmaf(w1.x,q1.x, a1))));
      float4 w2 = *(const float4*)(wrow + ((k4+2) << 2));
      float4 q2 = *(const float4*)(hb + (((k4+2) ^ bx) << 2));
      a2 = fmaf(w2.w,q2.w, fmaf(w2.z,q2.z, fmaf(w2.y,q2.y, fmaf(w2.x,q2.x, a2))));
      float4 w3 = *(const float4*)(wrow + ((k4+3) << 2));
      float4 q3 = *(const float4*)(hb + (((k4+3) ^ bx) << 2));
      a3 = fmaf(w3.w,q3.w, fmaf(w3.z,q3.z, fmaf(w3.y,q3.y, fmaf(w3.x,q3.x, a3))));
    }
    gsh[jj][gate][b] = xterm + ((a0 + a1) + (a2 + a3));
    __syncthreads();
    if (tid < 64){
      int b2 = tid & 31, jj2 = tid >> 5;
      float iv = sigm (gsh[jj2][0][b2]);
      float fv = sigm (gsh[jj2][1][b2]);
      float gv = tanh_(gsh[jj2][2][b2]);
      float ov = sigm (gsh[jj2][3][b2]);
      creg = fv * creg + iv * gv;
      float hnew = ov * tanh_(creg);
      cstore(hdst + (size_t)b2 * H + bk * 2 + jj2, hnew);
    }
    gbar(bars, ++bar);
    // ---------------- phase B: dp = h_t @ W2^T (blocks 0..127) ----
    if (bk < 128){
      for (int i = tid; i < BH / 4; i += 256){
        int bb = i >> 7, k4 = i & 127;
        const float* src = hdst + (size_t)bb * H + (k4 << 2);
        float4 vv;
        vv.x = cload(src+0); vv.y = cload(src+1); vv.z = cload(src+2); vv.w = cload(src+3);
        *(float4*)&hsh[bb * H + ((k4 ^ (bb & 7)) << 2)] = vv;
      }
      __syncthreads();
      int kq = tid >> 7, nn = (tid >> 5) & 3, b2 = tid & 31;
      int n = bk * 4 + nn;
      const float* w = W2 + (size_t)n * H + kq * 256;
      const float* hb2 = hsh + b2 * H;
      int bx2 = b2 & 7;
      float p0 = 0.f, p1 = 0.f;
      #pragma unroll 2
      for (int k4 = 0; k4 < 64; k4 += 2){
        float4 w0 = *(const float4*)(w + ((k4+0) << 2));
        int kk0 = kq * 64 + k4 + 0;
        float4 h0 = *(const float4*)(hb2 + ((kk0 ^ bx2) << 2));
        p0 = fmaf(w0.w,h0.w, fmaf(w0.z,h0.z, fmaf(w0.y,h0.y, fmaf(w0.x,h0.x, p0))));
        float4 w1 = *(const float4*)(w + ((k4+1) << 2));
        int kk1 = kq * 64 + k4 + 1;
        float4 h1 = *(const float4*)(hb2 + ((kk1 ^ bx2) << 2));
        p1 = fmaf(w1.w,h1.w, fmaf(w1.z,h1.z, fmaf(w1.y,h1.y, fmaf(w1.x,h1.x, p1))));
      }
      gshB[kq][nn][b2] = p0 + p1;
      __syncthreads();
      if (tid < 128){
        int nn2 = tid >> 5, b3 = tid & 31;
        cstore(dp + (size_t)b3 * H + bk * 4 + nn2, gshB[0][nn2][b3] + gshB[1][nn2][b3]);
      }
    }
    gbar(bars, ++bar);
    // ---------------- phase C: attention + softmax + argmax (blocks 0..31) ---
    if (bk < 32){
      dpsh[tid]       = cload(dp + (size_t)bk * H + tid);
      dpsh[tid + 256] = cload(dp + (size_t)bk * H + 256 + tid);
      __syncthreads();
      int s = tid & 127, half = tid >> 7;
      const float* Pp = Pt + ((size_t)bk * H + half * 256) * S + s;
      float c0=0.f,c1=0.f,c2=0.f,c3=0.f;
      #pragma unroll 2
      for (int h = 0; h < 256; h += 4){
        float x0 = Pp[(size_t)(h+0) * S] + dpsh[half*256 + h + 0];
        c0 += vsh[half*256 + h + 0] * tanh_(x0);
        float x1 = Pp[(size_t)(h+1) * S] + dpsh[half*256 + h + 1];
        c1 += vsh[half*256 + h + 1] * tanh_(x1);
        float x2 = Pp[(size_t)(h+2) * S] + dpsh[half*256 + h + 2];
        c2 += vsh[half*256 + h + 2] * tanh_(x2);
        float x3 = Pp[(size_t)(h+3) * S] + dpsh[half*256 + h + 3];
        c3 += vsh[half*256 + h + 3] * tanh_(x3);
      }
      scsh[half][s] = (c0 + c1) + (c2 + c3);
      __syncthreads();
      float sc = 0.f;
      if (tid < 128){
        sc = scsh[0][tid] + scsh[1][tid];
        rv[tid] = sc; ri[tid] = tid;
      }
      __syncthreads();
      for (int off = 64; off > 0; off >>= 1){
        if (tid < off){
          float v2 = rv[tid + off]; int i2 = ri[tid + off];
          if (v2 > rv[tid] || (v2 == rv[tid] && i2 < ri[tid])){ rv[tid] = v2; ri[tid] = i2; }
        }
        __syncthreads();
      }
      float m = rv[0]; int am = ri[0];
      __syncthreads();
      if (tid < 128) rv[tid] = __expf(sc - m);
      __syncthreads();
      for (int off = 64; off > 0; off >>= 1){
        if (tid < off) rv[tid] += rv[tid + off];
        __syncthreads();
      }
      float lse = __logf(rv[0]);
      if (tid < 128) out[((size_t)bk * S + t) * S + tid] = sc - m - lse;
      if (tid == 0) cstorei(top_idx + bk, am);
    }
    gbar(bars, ++bar);
  }
}

extern "C" void kernel_launch(void* const* d_in, const int* in_sizes, int n_in,
                              void* d_out, int out_size, void* d_ws, size_t ws_size,
                              hipStream_t stream) {
  const float* inputs  = (const float*)d_in[0];
  const float* Wp      = (const float*)d_in[1];
  const float* bp      = (const float*)d_in[2];
  const float* eWih    = (const float*)d_in[3];
  const float* eWhh    = (const float*)d_in[4];
  const float* ebih    = (const float*)d_in[5];
  const float* ebhh    = (const float*)d_in[6];
  const float* dWih    = (const float*)d_in[7];
  const float* dWhh    = (const float*)d_in[8];
  const float* dbih    = (const float*)d_in[9];
  const float* dbhh    = (const float*)d_in[10];
  const float* W1      = (const float*)d_in[11];
  const float* W2      = (const float*)d_in[12];
  const float* v       = (const float*)d_in[13];
  float* out = (float*)d_out;

  float* ws = (float*)d_ws;
  float* E      = ws + OFF_E;
  float* D      = ws + OFF_D;
  float* enc_out= ws + OFF_EO;
  float* Pt     = ws + OFF_PT;
  float* h_pp   = ws + OFF_H;
  float* c_buf  = ws + OFF_C;
  float* dp     = ws + OFF_DP;
  float* M1     = ws + OFF_M1;
  float* bias_e = ws + OFF_BE;
  float* dbias  = ws + OFF_DB;
  int*      top_idx = (int*)(ws + OFF_END);
  unsigned* bars_e  = (unsigned*)(top_idx + 32);
  unsigned* bars_d  = bars_e + BAR_U32;

  // zero h0 (buf0) + top_idx + both barrier areas (deterministic per launch)
  hipMemsetAsync(h_pp, 0, (size_t)BH * sizeof(float), stream);
  hipMemsetAsync(top_idx, 0, (32 + 2 * BAR_U32) * sizeof(int), stream);

  prep_misc<<<G4 / 256, 256, 0, stream>>>(eWih, Wp, bp, ebih, ebhh, dbih, dbhh,
                                          M1, bias_e, dbias);
  efill<<<(int)(SZ_E / 256), 256, 0, stream>>>(inputs, M1, bias_e, E);

  encoder_kernel<<<256, 256, 0, stream>>>(eWhh, E, h_pp, c_buf, enc_out, bars_e);

  {
    dim3 grid(G4 / 64, (B * S) / 64);
    gemm_nt<0><<<grid, 256, 0, stream>>>(enc_out, dWih, dbias, D, B * S, G4, H);
  }
  {
    dim3 grid(H / 64, (B * S) / 64);
    gemm_nt<1><<<grid, 256, 0, stream>>>(enc_out, W1, nullptr, Pt, B * S, H, H);
  }

  decoder_kernel<<<256, 256, 0, stream>>>(dWhh, D, dbias, W2, Pt, v,
                                          h_pp, c_buf, dp, top_idx, out, bars_d);
  (void)in_sizes; (void)n_in; (void)out_size; (void)ws_size;
}

// Round 3
// 5631.807 us; speedup vs baseline: 2.5157x; 1.1132x over previous
//
#include <hip/hip_runtime.h>
#include <math.h>

// Problem constants
static constexpr int H  = 512;
static constexpr int B  = 32;
static constexpr int S  = 128;
static constexpr int G4 = 2048;  // 4*H
static constexpr int BH = B * H;

// ws layout (in floats)
static constexpr size_t OFF_E  = 0;                       // [t][c][b] : S*G4*B
static constexpr size_t SZ_E   = (size_t)S * G4 * B;
static constexpr size_t OFF_D  = OFF_E + SZ_E;            // [b][t][c] : B*S*G4
static constexpr size_t SZ_D   = (size_t)B * S * G4;
static constexpr size_t OFF_EO = OFF_D + SZ_D;            // enc_out [b][t][h]
static constexpr size_t SZ_EO  = (size_t)B * S * H;
static constexpr size_t OFF_PT = OFF_EO + SZ_EO;          // P_t [b][h][s]
static constexpr size_t SZ_PT  = (size_t)B * H * S;
static constexpr size_t OFF_H  = OFF_PT + SZ_PT;          // h ping-pong [2][b][h]
static constexpr size_t OFF_C  = OFF_H + 2 * (size_t)BH;  // c_buf [b][h]
static constexpr size_t OFF_DP = OFF_C + (size_t)BH;      // dp [b][h]
static constexpr size_t OFF_M1 = OFF_DP + (size_t)BH;     // M1 [c][2]
static constexpr size_t OFF_BE = OFF_M1 + (size_t)G4 * 2; // bias_e [c]
static constexpr size_t OFF_DB = OFF_BE + G4;             // dbias [c]
static constexpr size_t OFF_END= OFF_DB + G4;             // floats end
// int region at OFF_END: top_idx[32], then 2 barrier areas.
// Barrier area layout (u32): slot[bk] at [bk*32] (one 128B line per block),
// go replicas at [8192 + g*32], g=0..7.
static constexpr int BAR_U32 = 8192 + 8 * 32;  // 8448

__device__ __forceinline__ float sigm(float x){
  float e = __expf(-x);
  return 1.0f / (1.0f + e);
}
__device__ __forceinline__ float tanh_(float x){
  float e = __expf(2.0f * x);
  return 1.0f - 2.0f / (1.0f + e);
}

// coherent-point (device-scope) accessors: bypass stale L1/L2, no fences
__device__ __forceinline__ float2 cload2(const float* p){
  union { unsigned long long u; float2 f; } c;
  c.u = __hip_atomic_load((const unsigned long long*)p, __ATOMIC_RELAXED,
                          __HIP_MEMORY_SCOPE_AGENT);
  return c.f;
}
__device__ __forceinline__ void cstore(float* p, float v){
  __hip_atomic_store(p, v, __ATOMIC_RELAXED, __HIP_MEMORY_SCOPE_AGENT);
}
__device__ __forceinline__ int cloadi(const int* p){
  return __hip_atomic_load(p, __ATOMIC_RELAXED, __HIP_MEMORY_SCOPE_AGENT);
}
__device__ __forceinline__ void cstorei(int* p, int v){
  __hip_atomic_store(p, v, __ATOMIC_RELAXED, __HIP_MEMORY_SCOPE_AGENT);
}

// -------- slot-based fence-free grid barrier (grid = 256 blocks) --------
// No atomic RMW anywhere: arrivals are parallel stores to private lines;
// master (block 0) detects via 255 parallel polls; release via 8 go lines.
// Correctness: __syncthreads() drains vmcnt(0) in every wave before
// s_barrier, so all this block's agent-scope data stores are at the
// coherence point before the arrival store issues.
__device__ __forceinline__ void gbar(unsigned* area, unsigned ep){
  __syncthreads();
  const int tid = threadIdx.x;
  if (blockIdx.x == 0){
    if (tid > 0){
      while (__hip_atomic_load(area + tid * 32, __ATOMIC_RELAXED,
                               __HIP_MEMORY_SCOPE_AGENT) < ep){}
    }
    __syncthreads();
    if (tid < 8)
      __hip_atomic_store(area + 8192 + tid * 32, ep, __ATOMIC_RELAXED,
                         __HIP_MEMORY_SCOPE_AGENT);
    __syncthreads();
  } else {
    if (tid == 0){
      __hip_atomic_store(area + blockIdx.x * 32, ep, __ATOMIC_RELAXED,
                         __HIP_MEMORY_SCOPE_AGENT);
    } else if (tid == 64){
      while (__hip_atomic_load(area + 8192 + (blockIdx.x & 7) * 32,
                               __ATOMIC_RELAXED, __HIP_MEMORY_SCOPE_AGENT) < ep){}
    }
    __syncthreads();
  }
}

// -------- prep: M1 = Wih@Wp, bias_e = Wih@bp + bih + bhh, dbias --------
__global__ __launch_bounds__(256) void prep_misc(
    const float* __restrict__ eWih, const float* __restrict__ Wp,
    const float* __restrict__ bp,  const float* __restrict__ ebih,
    const float* __restrict__ ebhh, const float* __restrict__ dbih,
    const float* __restrict__ dbhh,
    float* __restrict__ M1, float* __restrict__ bias_e, float* __restrict__ dbias)
{
  int c = blockIdx.x * 256 + threadIdx.x;   // 0..2047
  const float* wr = eWih + (size_t)c * H;
  float m0 = 0.f, m1 = 0.f, mb = 0.f;
  for (int k = 0; k < H; k += 4){
    float4 w  = *(const float4*)(wr + k);
    float4 p0 = *(const float4*)(Wp + (size_t)k * 2);
    float4 p1 = *(const float4*)(Wp + (size_t)(k + 2) * 2);
    float4 bb = *(const float4*)(bp + k);
    m0 += w.x*p0.x + w.y*p0.z + w.z*p1.x + w.w*p1.z;
    m1 += w.x*p0.y + w.y*p0.w + w.z*p1.y + w.w*p1.w;
    mb += w.x*bb.x + w.y*bb.y + w.z*bb.z + w.w*bb.w;
  }
  M1[(size_t)c*2]   = m0;
  M1[(size_t)c*2+1] = m1;
  bias_e[c] = ebih[c] + ebhh[c] + mb;
  dbias[c]  = dbih[c] + dbhh[c];
}

// -------- E fill: E[t][c][b] = M1[c]·in[b,t] + bias_e[c] --------
__global__ __launch_bounds__(256) void efill(
    const float* __restrict__ inp, const float* __restrict__ M1,
    const float* __restrict__ be, float* __restrict__ E)
{
  size_t i = (size_t)blockIdx.x * 256 + threadIdx.x;
  int b = (int)(i & 31);
  int c = (int)((i >> 5) & 2047);
  int t = (int)(i >> 16);
  float x0 = inp[((size_t)b * S + t) * 2 + 0];
  float x1 = inp[((size_t)b * S + t) * 2 + 1];
  E[i] = M1[(size_t)c*2] * x0 + M1[(size_t)c*2+1] * x1 + be[c];
}

// -------- generic fp32 GEMM: C = A(MxK) @ B(NxK)^T (+bias) --------
template<int LAYOUT>
__global__ __launch_bounds__(256) void gemm_nt(
    const float* __restrict__ A, const float* __restrict__ Bm,
    const float* __restrict__ bias, float* __restrict__ C,
    int M, int N, int K)
{
  __shared__ float As[16][68];
  __shared__ float Bs[16][68];
  int tid = threadIdx.x;
  int bm = blockIdx.y * 64, bn = blockIdx.x * 64;
  int tm = (tid & 15) * 4, tn = (tid >> 4) * 4;
  float acc[4][4] = {};
  int r  = tid >> 2;
  int kq = (tid & 3) * 4;
  for (int k0 = 0; k0 < K; k0 += 16){
    float4 a = *(const float4*)(A  + (size_t)(bm + r) * K + k0 + kq);
    float4 b = *(const float4*)(Bm + (size_t)(bn + r) * K + k0 + kq);
    __syncthreads();
    As[kq+0][r] = a.x; As[kq+1][r] = a.y; As[kq+2][r] = a.z; As[kq+3][r] = a.w;
    Bs[kq+0][r] = b.x; Bs[kq+1][r] = b.y; Bs[kq+2][r] = b.z; Bs[kq+3][r] = b.w;
    __syncthreads();
    #pragma unroll
    for (int kk = 0; kk < 16; ++kk){
      float4 av = *(const float4*)(&As[kk][tm]);
      float4 bv = *(const float4*)(&Bs[kk][tn]);
      acc[0][0] += av.x*bv.x; acc[0][1] += av.x*bv.y; acc[0][2] += av.x*bv.z; acc[0][3] += av.x*bv.w;
      acc[1][0] += av.y*bv.x; acc[1][1] += av.y*bv.y; acc[1][2] += av.y*bv.z; acc[1][3] += av.y*bv.w;
      acc[2][0] += av.z*bv.x; acc[2][1] += av.z*bv.y; acc[2][2] += av.z*bv.z; acc[2][3] += av.z*bv.w;
      acc[3][0] += av.w*bv.x; acc[3][1] += av.w*bv.y; acc[3][2] += av.w*bv.z; acc[3][3] += av.w*bv.w;
    }
  }
  #pragma unroll
  for (int i = 0; i < 4; ++i){
    int m = bm + tm + i;
    #pragma unroll
    for (int j = 0; j < 4; ++j){
      int n = bn + tn + j;
      float vv = acc[i][j] + (bias ? bias[n] : 0.f);
      if (LAYOUT == 0) C[(size_t)m * N + n] = vv;
      else             C[((size_t)(m >> 7) * 512 + n) * 128 + (m & 127)] = vv;
    }
  }
}

// stage h (coherent, [B][H]) into swizzled LDS, 8B-vectorized
__device__ __forceinline__ void stage_h(const float* hsrc, float* hsh, int tid){
  #pragma unroll
  for (int i = tid; i < BH / 4; i += 256){
    int bb = i >> 7, k4 = i & 127;
    const float* src = hsrc + (size_t)bb * H + (k4 << 2);
    float2 lo = cload2(src), hi = cload2(src + 2);
    float4 vv; vv.x = lo.x; vv.y = lo.y; vv.z = hi.x; vv.w = hi.y;
    *(float4*)&hsh[bb * H + ((k4 ^ (bb & 7)) << 2)] = vv;
  }
}

// -------- persistent encoder --------
__global__ __launch_bounds__(256) void encoder_kernel(
    const float* __restrict__ Whh,
    const float* __restrict__ E,     // [t][c][b]
    float* __restrict__ h_pp,        // [2][B][H] ping-pong
    float* __restrict__ c_buf,
    float* __restrict__ enc_out, unsigned* __restrict__ bars)
{
  __shared__ float hsh[BH];
  __shared__ float gsh[2][4][B];
  const int tid = threadIdx.x, bk = blockIdx.x;
  const int b = tid & 31, gate = (tid >> 5) & 3, jj = tid >> 7;
  const int row = gate * H + bk * 2 + jj;
  const float* wrow = Whh + (size_t)row * H;
  const int bx = b & 7;
  float creg = 0.f;
  unsigned bar = 0;
  for (int t = 0; t < S; ++t){
    const float* hsrc = h_pp + (size_t)(t & 1) * BH;
    float*       hdst = h_pp + (size_t)((t & 1) ^ 1) * BH;
    stage_h(hsrc, hsh, tid);
    __syncthreads();
    float ev = E[((size_t)t * G4 + row) * B + b];
    float a0=0.f,a1=0.f,a2=0.f,a3=0.f;
    const float* hb = hsh + b * H;
    #pragma unroll 2
    for (int k4 = 0; k4 < 128; k4 += 4){
      float4 w0 = *(const float4*)(wrow + ((k4+0) << 2));
      float4 q0 = *(const float4*)(hb + (((k4+0) ^ bx) << 2));
      a0 = fmaf(w0.w,q0.w, fmaf(w0.z,q0.z, fmaf(w0.y,q0.y, fmaf(w0.x,q0.x, a0))));
      float4 w1 = *(const float4*)(wrow + ((k4+1) << 2));
      float4 q1 = *(const float4*)(hb + (((k4+1) ^ bx) << 2));
      a1 = fmaf(w1.w,q1.w, fmaf(w1.z,q1.z, fmaf(w1.y,q1.y, fmaf(w1.x,q1.x, a1))));
      float4 w2 = *(const float4*)(wrow + ((k4+2) << 2));
      float4 q2 = *(const float4*)(hb + (((k4+2) ^ bx) << 2));
      a2 = fmaf(w2.w,q2.w, fmaf(w2.z,q2.z, fmaf(w2.y,q2.y, fmaf(w2.x,q2.x, a2))));
      float4 w3 = *(const float4*)(wrow + ((k4+3) << 2));
      float4 q3 = *(const float4*)(hb + (((k4+3) ^ bx) << 2));
      a3 = fmaf(w3.w,q3.w, fmaf(w3.z,q3.z, fmaf(w3.y,q3.y, fmaf(w3.x,q3.x, a3))));
    }
    gsh[jj][gate][b] = ev + ((a0 + a1) + (a2 + a3));
    __syncthreads();
    if (tid < 64){
      int b2 = tid & 31, jj2 = tid >> 5;
      float iv = sigm (gsh[jj2][0][b2]);
      float fv = sigm (gsh[jj2][1][b2]);
      float gv = tanh_(gsh[jj2][2][b2]);
      float ov = sigm (gsh[jj2][3][b2]);
      creg = fv * creg + iv * gv;
      float hnew = ov * tanh_(creg);
      int j2 = bk * 2 + jj2;
      cstore(hdst + (size_t)b2 * H + j2, hnew);
      enc_out[((size_t)b2 * S + t) * H + j2] = hnew;
    }
    gbar(bars, ++bar);
  }
  if (tid < 64){
    int b2 = tid & 31, jj2 = tid >> 5;
    c_buf[(size_t)b2 * H + bk * 2 + jj2] = creg;
  }
}

// -------- persistent decoder --------
__global__ __launch_bounds__(256) void decoder_kernel(
    const float* __restrict__ Whh,
    const float* __restrict__ D,      // [b][t][c]
    const float* __restrict__ dbias,
    const float* __restrict__ W2,
    const float* __restrict__ Pt,     // [b][h][s]
    const float* __restrict__ v,
    float* __restrict__ h_pp,         // [2][B][H]; enc final h in buf0
    float* __restrict__ c_buf,
    float* __restrict__ dp, int* __restrict__ top_idx,
    float* __restrict__ out, unsigned* __restrict__ bars)
{
  __shared__ float hsh[BH];
  __shared__ float gsh[2][4][B];
  __shared__ float gshB[2][4][B];
  __shared__ float dpsh[H];
  __shared__ float vsh[H];
  __shared__ float scsh[2][S];
  __shared__ float rv[S];
  __shared__ int   ri[S];
  const int tid = threadIdx.x, bk = blockIdx.x;
  const int b = tid & 31, gate = (tid >> 5) & 3, jj = tid >> 7;
  const int row = gate * H + bk * 2 + jj;
  const float* wrow = Whh + (size_t)row * H;
  const int bx = b & 7;
  float creg = 0.f;
  if (tid < 64) creg = c_buf[(size_t)(tid & 31) * H + bk * 2 + (tid >> 5)];
  if (bk < 32){ vsh[tid] = v[tid]; vsh[tid + 256] = v[tid + 256]; }
  unsigned bar = 0;
  for (int t = 0; t < S; ++t){
    const float* hsrc = h_pp + (size_t)(t & 1) * BH;
    float*       hdst = h_pp + (size_t)((t & 1) ^ 1) * BH;
    // ---------------- phase A: gates + pointwise ----------------
    stage_h(hsrc, hsh, tid);
    __syncthreads();
    float xterm;
    if (t == 0) xterm = dbias[row];
    else        xterm = D[((size_t)b * S + cloadi(top_idx + b)) * G4 + row];
    float a0=0.f,a1=0.f,a2=0.f,a3=0.f;
    const float* hb = hsh + b * H;
    #pragma unroll 2
    for (int k4 = 0; k4 < 128; k4 += 4){
      float4 w0 = *(const float4*)(wrow + ((k4+0) << 2));
      float4 q0 = *(const float4*)(hb + (((k4+0) ^ bx) << 2));
      a0 = fmaf(w0.w,q0.w, fmaf(w0.z,q0.z, fmaf(w0.y,q0.y, fmaf(w0.x,q0.x, a0))));
      float4 w1 = *(const float4*)(wrow + ((k4+1) << 2));
      float4 q1 = *(const float4*)(hb + (((k4+1) ^ bx) << 2));
      a1 = fmaf(w1.w,q1.w, fmaf(w1.z,q1.z, fmaf(w1.y,q1.y, fmaf(w1.x,q1.x, a1))));
      float4 w2 = *(const float4*)(wrow + ((k4+2) << 2));
      float4 q2 = *(const float4*)(hb + (((k4+2) ^ bx) << 2));
      a2 = fmaf(w2.w,q2.w, fmaf(w2.z,q2.z, fmaf(w2.y,q2.y, fmaf(w2.x,q2.x, a2))));
      float4 w3 = *(const float4*)(wrow + ((k4+3) << 2));
      float4 q3 = *(const float4*)(hb + (((k4+3) ^ bx) << 2));
      a3 = fmaf(w3.w,q3.w, fmaf(w3.z,q3.z, fmaf(w3.y,q3.y, fmaf(w3.x,q3.x, a3))));
    }
    gsh[jj][gate][b] = xterm + ((a0 + a1) + (a2 + a3));
    __syncthreads();
    if (tid < 64){
      int b2 = tid & 31, jj2 = tid >> 5;
      float iv = sigm (gsh[jj2][0][b2]);
      float fv = sigm (gsh[jj2][1][b2]);
      float gv = tanh_(gsh[jj2][2][b2]);
      float ov = sigm (gsh[jj2][3][b2]);
      creg = fv * creg + iv * gv;
      float hnew = ov * tanh_(creg);
      cstore(hdst + (size_t)b2 * H + bk * 2 + jj2, hnew);
    }
    gbar(bars, ++bar);
    // ---------------- phase B: dp = h_t @ W2^T (blocks 0..127) ----
    if (bk < 128){
      stage_h(hdst, hsh, tid);
      __syncthreads();
      int kq = tid >> 7, nn = (tid >> 5) & 3, b2 = tid & 31;
      int n = bk * 4 + nn;
      const float* w = W2 + (size_t)n * H + kq * 256;
      const float* hb2 = hsh + b2 * H;
      int bx2 = b2 & 7;
      float p0 = 0.f, p1 = 0.f;
      #pragma unroll 2
      for (int k4 = 0; k4 < 64; k4 += 2){
        float4 w0 = *(const float4*)(w + ((k4+0) << 2));
        int kk0 = kq * 64 + k4 + 0;
        float4 h0 = *(const float4*)(hb2 + ((kk0 ^ bx2) << 2));
        p0 = fmaf(w0.w,h0.w, fmaf(w0.z,h0.z, fmaf(w0.y,h0.y, fmaf(w0.x,h0.x, p0))));
        float4 w1 = *(const float4*)(w + ((k4+1) << 2));
        int kk1 = kq * 64 + k4 + 1;
        float4 h1 = *(const float4*)(hb2 + ((kk1 ^ bx2) << 2));
        p1 = fmaf(w1.w,h1.w, fmaf(w1.z,h1.z, fmaf(w1.y,h1.y, fmaf(w1.x,h1.x, p1))));
      }
      gshB[kq][nn][b2] = p0 + p1;
      __syncthreads();
      if (tid < 128){
        int nn2 = tid >> 5, b3 = tid & 31;
        cstore(dp + (size_t)b3 * H + bk * 4 + nn2, gshB[0][nn2][b3] + gshB[1][nn2][b3]);
      }
    }
    gbar(bars, ++bar);
    // ---------------- phase C: attention + softmax + argmax (blocks 0..31) ---
    if (bk < 32){
      float2 d0 = cload2(dp + (size_t)bk * H + 2 * tid);
      dpsh[2 * tid]     = d0.x;
      dpsh[2 * tid + 1] = d0.y;
      __syncthreads();
      int s = tid & 127, half = tid >> 7;
      const float* Pp = Pt + ((size_t)bk * H + half * 256) * S + s;
      float c0=0.f,c1=0.f,c2=0.f,c3=0.f;
      #pragma unroll 2
      for (int h = 0; h < 256; h += 4){
        float x0 = Pp[(size_t)(h+0) * S] + dpsh[half*256 + h + 0];
        c0 += vsh[half*256 + h + 0] * tanh_(x0);
        float x1 = Pp[(size_t)(h+1) * S] + dpsh[half*256 + h + 1];
        c1 += vsh[half*256 + h + 1] * tanh_(x1);
        float x2 = Pp[(size_t)(h+2) * S] + dpsh[half*256 + h + 2];
        c2 += vsh[half*256 + h + 2] * tanh_(x2);
        float x3 = Pp[(size_t)(h+3) * S] + dpsh[half*256 + h + 3];
        c3 += vsh[half*256 + h + 3] * tanh_(x3);
      }
      scsh[half][s] = (c0 + c1) + (c2 + c3);
      __syncthreads();
      float sc = 0.f;
      if (tid < 128){
        sc = scsh[0][tid] + scsh[1][tid];
        rv[tid] = sc; ri[tid] = tid;
      }
      __syncthreads();
      for (int off = 64; off > 0; off >>= 1){
        if (tid < off){
          float v2 = rv[tid + off]; int i2 = ri[tid + off];
          if (v2 > rv[tid] || (v2 == rv[tid] && i2 < ri[tid])){ rv[tid] = v2; ri[tid] = i2; }
        }
        __syncthreads();
      }
      float m = rv[0]; int am = ri[0];
      __syncthreads();
      if (tid < 128) rv[tid] = __expf(sc - m);
      __syncthreads();
      for (int off = 64; off > 0; off >>= 1){
        if (tid < off) rv[tid] += rv[tid + off];
        __syncthreads();
      }
      float lse = __logf(rv[0]);
      if (tid < 128) out[((size_t)bk * S + t) * S + tid] = sc - m - lse;
      if (tid == 0) cstorei(top_idx + bk, am);
    }
    gbar(bars, ++bar);
  }
}

extern "C" void kernel_launch(void* const* d_in, const int* in_sizes, int n_in,
                              void* d_out, int out_size, void* d_ws, size_t ws_size,
                              hipStream_t stream) {
  const float* inputs  = (const float*)d_in[0];
  const float* Wp      = (const float*)d_in[1];
  const float* bp      = (const float*)d_in[2];
  const float* eWih    = (const float*)d_in[3];
  const float* eWhh    = (const float*)d_in[4];
  const float* ebih    = (const float*)d_in[5];
  const float* ebhh    = (const float*)d_in[6];
  const float* dWih    = (const float*)d_in[7];
  const float* dWhh    = (const float*)d_in[8];
  const float* dbih    = (const float*)d_in[9];
  const float* dbhh    = (const float*)d_in[10];
  const float* W1      = (const float*)d_in[11];
  const float* W2      = (const float*)d_in[12];
  const float* v       = (const float*)d_in[13];
  float* out = (float*)d_out;

  float* ws = (float*)d_ws;
  float* E      = ws + OFF_E;
  float* D      = ws + OFF_D;
  float* enc_out= ws + OFF_EO;
  float* Pt     = ws + OFF_PT;
  float* h_pp   = ws + OFF_H;
  float* c_buf  = ws + OFF_C;
  float* dp     = ws + OFF_DP;
  float* M1     = ws + OFF_M1;
  float* bias_e = ws + OFF_BE;
  float* dbias  = ws + OFF_DB;
  int*      top_idx = (int*)(ws + OFF_END);
  unsigned* bars_e  = (unsigned*)(top_idx + 32);
  unsigned* bars_d  = bars_e + BAR_U32;

  // zero h0 (buf0) + top_idx + both barrier areas (deterministic per launch)
  hipMemsetAsync(h_pp, 0, (size_t)BH * sizeof(float), stream);
  hipMemsetAsync(top_idx, 0, (32 + 2 * BAR_U32) * sizeof(int), stream);

  prep_misc<<<G4 / 256, 256, 0, stream>>>(eWih, Wp, bp, ebih, ebhh, dbih, dbhh,
                                          M1, bias_e, dbias);
  efill<<<(int)(SZ_E / 256), 256, 0, stream>>>(inputs, M1, bias_e, E);

  encoder_kernel<<<256, 256, 0, stream>>>(eWhh, E, h_pp, c_buf, enc_out, bars_e);

  {
    dim3 grid(G4 / 64, (B * S) / 64);
    gemm_nt<0><<<grid, 256, 0, stream>>>(enc_out, dWih, dbias, D, B * S, G4, H);
  }
  {
    dim3 grid(H / 64, (B * S) / 64);
    gemm_nt<1><<<grid, 256, 0, stream>>>(enc_out, W1, nullptr, Pt, B * S, H, H);
  }

  decoder_kernel<<<256, 256, 0, stream>>>(dWhh, D, dbias, W2, Pt, v,
                                          h_pp, c_buf, dp, top_idx, out, bars_d);
  (void)in_sizes; (void)n_in; (void)out_size; (void)ws_size;
}